// Round 12
// baseline (76.894 us; speedup 1.0000x reference)
//
#include <hip/hip_runtime.h>
#include <hip/hip_fp16.h>

#define N_NODES 50000
#define N_EDGES 800000
#define D_IN 64
#define MAXD 64
#define BSHIFT 7                       // 128 nodes per bucket
#define BNODES 128
#define NBUCKET 391                    // ceil(50000/128)
#define BCAP 4096                      // staging slots per bucket (mean 2046)
#define NSCB 128                       // scatter blocks
#define EPB (N_EDGES / NSCB)           // 6250 edges per scatter block
#define LIN1B ((N_NODES + 63) / 64)    // 782 lin1 blocks

typedef _Float16 f16x8 __attribute__((ext_vector_type(8)));
typedef float f32x4 __attribute__((ext_vector_type(4)));

union H8 { uint4 v; unsigned int u[4]; f16x8 h; };

__device__ __forceinline__ f32x4 MM(const H8& a, const H8& b, f32x4 c) {
    return __builtin_amdgcn_mfma_f32_16x16x32_f16(a.h, b.h, c, 0, 0, 0);
}
__device__ __forceinline__ unsigned int pkh(float a, float b) {
    __half2 h = __floats2half2_rn(a, b);
    unsigned int u;
    __builtin_memcpy(&u, &h, 4);
    return u;
}

// ---- K1 (fused): blocks [0,NSCB) = bucket-scatter; rest = MFMA lin1 ----
__global__ __launch_bounds__(256) void k_scat_lin1(
        const int* __restrict__ src, const int* __restrict__ dst,
        int* __restrict__ bucketCnt, unsigned int* __restrict__ staging,
        const float* __restrict__ x,
        const float* __restrict__ w1n, const float* __restrict__ w1r,
        const float* __restrict__ b1,
        __half* __restrict__ xw1n, __half* __restrict__ xr1b) {
    __shared__ __align__(16) unsigned char smem[8192];
    const int tid = threadIdx.x;

    if (blockIdx.x < NSCB) {
        // ---------- scatter role ----------
        int* lh   = (int*)smem;            // [NBUCKET] local hist / cursor
        int* lofs = lh + NBUCKET;          // [NBUCKET] reserved global offset
        for (int i = tid; i < NBUCKET; i += 256) lh[i] = 0;
        __syncthreads();
        const int base = blockIdx.x * EPB;
        for (int i = tid; i < EPB; i += 256)
            atomicAdd(&lh[dst[base + i] >> BSHIFT], 1);
        __syncthreads();
        for (int i = tid; i < NBUCKET; i += 256) {
            int c = lh[i];
            lofs[i] = c ? atomicAdd(&bucketCnt[i], c) : 0;
            lh[i] = 0;                     // reuse as local cursor
        }
        __syncthreads();
        for (int i = tid; i < EPB; i += 256) {
            int d = dst[base + i], s = src[base + i];
            int b = d >> BSHIFT;
            int pos = lofs[b] + atomicAdd(&lh[b], 1);
            if (pos < BCAP)
                staging[b * BCAP + pos] =
                    ((unsigned int)(d & (BNODES - 1)) << 16) | (unsigned int)s;
        }
    } else {
        // ---------- lin1 role (MFMA): wave = 16 nodes ----------
        __half* s_w1t = (__half*)smem;     // [out 32][k 64 pad 72]
        for (int i = tid; i < 2048; i += 256) {
            int o = i & 31, k = i >> 5;
            float v = (o < 16) ? w1n[k * 16 + o] : w1r[k * 16 + (o - 16)];
            s_w1t[o * 72 + k] = __float2half(v);
        }
        __syncthreads();
        const int l = tid & 63, li = l & 15, g = l >> 4;
        const int wid = tid >> 6;
        const int node = (blockIdx.x - NSCB) * 64 + wid * 16 + li;
        const int nodec = node < N_NODES ? node : N_NODES - 1;

        H8 B0, B1;
        {
            const float4* xp = (const float4*)(x + nodec * 64 + 8 * g);
            float4 v0 = xp[0], v1 = xp[1];
            B0.u[0] = pkh(v0.x, v0.y); B0.u[1] = pkh(v0.z, v0.w);
            B0.u[2] = pkh(v1.x, v1.y); B0.u[3] = pkh(v1.z, v1.w);
            const float4* xq = (const float4*)(x + nodec * 64 + 32 + 8 * g);
            float4 w0 = xq[0], w1 = xq[1];
            B1.u[0] = pkh(w0.x, w0.y); B1.u[1] = pkh(w0.z, w0.w);
            B1.u[2] = pkh(w1.x, w1.y); B1.u[3] = pkh(w1.z, w1.w);
        }
        H8 A;
        f32x4 c0 = {0.f, 0.f, 0.f, 0.f};                   // -> xw1n
        A.v = *(const uint4*)(s_w1t + li * 72 + 8 * g);
        c0 = MM(A, B0, c0);
        A.v = *(const uint4*)(s_w1t + li * 72 + 32 + 8 * g);
        c0 = MM(A, B1, c0);
        f32x4 c1 = *(const f32x4*)(b1 + 4 * g);            // -> xr1b (+b1)
        A.v = *(const uint4*)(s_w1t + (16 + li) * 72 + 8 * g);
        c1 = MM(A, B0, c1);
        A.v = *(const uint4*)(s_w1t + (16 + li) * 72 + 32 + 8 * g);
        c1 = MM(A, B1, c1);

        if (node < N_NODES) {
            uint2 s0, s1;
            s0.x = pkh(c0[0], c0[1]); s0.y = pkh(c0[2], c0[3]);
            s1.x = pkh(c1[0], c1[1]); s1.y = pkh(c1[2], c1[3]);
            *(uint2*)(xw1n + node * 16 + 4 * g) = s0;
            *(uint2*)(xr1b + node * 16 + 4 * g) = s1;
        }
    }
}

// ---- K2: per-bucket table build in LDS + fused agg1 (h1 out) ----
__global__ __launch_bounds__(256) void k_buildAgg1(
        const unsigned int* __restrict__ staging,
        const int* __restrict__ bucketCnt,
        const __half* __restrict__ xw1n, const __half* __restrict__ xr1b,
        unsigned int* __restrict__ nbrU, int* __restrict__ deg,
        __half* __restrict__ h1) {
    __shared__ unsigned short ltbl[BNODES * MAXD];   // 16KB
    __shared__ int lcnt[BNODES];
    const int tid = threadIdx.x, b = blockIdx.x;
    if (tid < BNODES) lcnt[tid] = 0;
    __syncthreads();
    const int cnt = min(bucketCnt[b], BCAP);
    const unsigned int* st = staging + b * BCAP;
    for (int i = tid; i < cnt; i += 256) {
        unsigned int u = st[i];
        int dl = u >> 16, s = u & 0xFFFF;
        int slot = atomicAdd(&lcnt[dl], 1);
        if (slot < MAXD) ltbl[(dl << 6) + slot] = (unsigned short)s;
    }
    __syncthreads();
    const int nbase = b << BSHIFT;
    // write packed table (for agg2) + deg
    for (int i = tid; i < BNODES * 32; i += 256) {
        int nl = i >> 5, j = i & 31;
        int node = nbase + nl;
        if (node < N_NODES && 2 * j < lcnt[nl]) {
            unsigned int lo = ltbl[(nl << 6) + 2 * j];
            unsigned int hi = ltbl[(nl << 6) + 2 * j + 1];
            nbrU[(node << 5) + j] = lo | (hi << 16);
        }
    }
    if (tid < BNODES && nbase + tid < N_NODES) deg[nbase + tid] = lcnt[tid];
    // fused agg1: h1 = relu(mean_nbrs(xw1n) + xr1b); 8 half2-lanes per node
    for (int i = tid; i < BNODES * 8; i += 256) {
        int nl = i >> 3, fp = i & 7;
        int node = nbase + nl;
        if (node >= N_NODES) continue;
        int c = lcnt[nl];
        float inv = c > 0 ? 1.f / (float)c : 1.f;
        int cc = c > MAXD ? MAXD : c;
        const unsigned short* np = ltbl + (nl << 6);   // LDS broadcast reads
        float2 a0 = {0.f, 0.f}, a1 = {0.f, 0.f}, a2 = {0.f, 0.f}, a3 = {0.f, 0.f};
        int j = 0;
        for (; j + 4 <= cc; j += 4) {
            float2 v0 = __half22float2(*(const __half2*)(xw1n + (np[j + 0] << 4) + (fp << 1)));
            float2 v1 = __half22float2(*(const __half2*)(xw1n + (np[j + 1] << 4) + (fp << 1)));
            float2 v2 = __half22float2(*(const __half2*)(xw1n + (np[j + 2] << 4) + (fp << 1)));
            float2 v3 = __half22float2(*(const __half2*)(xw1n + (np[j + 3] << 4) + (fp << 1)));
            a0.x += v0.x; a0.y += v0.y; a1.x += v1.x; a1.y += v1.y;
            a2.x += v2.x; a2.y += v2.y; a3.x += v3.x; a3.y += v3.y;
        }
        for (; j < cc; ++j) {
            float2 v = __half22float2(*(const __half2*)(xw1n + (np[j] << 4) + (fp << 1)));
            a0.x += v.x; a0.y += v.y;
        }
        float2 r = __half22float2(*(const __half2*)(xr1b + (node << 4) + (fp << 1)));
        float rx = fmaxf((a0.x + a1.x + a2.x + a3.x) * inv + r.x, 0.f);
        float ry = fmaxf((a0.y + a1.y + a2.y + a3.y) * inv + r.y, 0.f);
        *(__half2*)(h1 + (node << 4) + (fp << 1)) = __floats2half2_rn(rx, ry);
    }
}

// ---- K3: agg2 = mean_nbrs(h1)  (half2 lanes) ----
__global__ __launch_bounds__(256) void k_agg2(
        const __half* __restrict__ h1,
        const int* __restrict__ deg, const unsigned short* __restrict__ nbr,
        __half* __restrict__ agg2) {
    const int t = blockIdx.x * 256 + threadIdx.x;
    if (t >= N_NODES * 8) return;
    const int node = t >> 3, fp = t & 7;
    int c = deg[node];
    float inv = c > 0 ? 1.f / (float)c : 1.f;
    int cc = c > MAXD ? MAXD : c;
    const unsigned short* np = nbr + (node << 6);
    float2 a0 = {0.f, 0.f}, a1 = {0.f, 0.f}, a2 = {0.f, 0.f}, a3 = {0.f, 0.f};
    int j = 0;
    for (; j + 4 <= cc; j += 4) {
        float2 v0 = __half22float2(*(const __half2*)(h1 + (np[j + 0] << 4) + (fp << 1)));
        float2 v1 = __half22float2(*(const __half2*)(h1 + (np[j + 1] << 4) + (fp << 1)));
        float2 v2 = __half22float2(*(const __half2*)(h1 + (np[j + 2] << 4) + (fp << 1)));
        float2 v3 = __half22float2(*(const __half2*)(h1 + (np[j + 3] << 4) + (fp << 1)));
        a0.x += v0.x; a0.y += v0.y; a1.x += v1.x; a1.y += v1.y;
        a2.x += v2.x; a2.y += v2.y; a3.x += v3.x; a3.y += v3.y;
    }
    for (; j < cc; ++j) {
        float2 v = __half22float2(*(const __half2*)(h1 + (np[j] << 4) + (fp << 1)));
        a0.x += v.x; a0.y += v.y;
    }
    *(__half2*)(agg2 + (node << 4) + (fp << 1)) =
        __floats2half2_rn((a0.x + a1.x + a2.x + a3.x) * inv,
                          (a0.y + a1.y + a2.y + a3.y) * inv);
}

// ---- K4 (k_head, MFMA): SAGE2 + MLP head, transposed D[out][node] ----
__global__ __launch_bounds__(256) void k_head(
        const __half* __restrict__ h1, const __half* __restrict__ agg2,
        const float* __restrict__ w2n, const float* __restrict__ w2r,
        const float* __restrict__ b2,
        const float* __restrict__ fw1, const float* __restrict__ fb1,
        const float* __restrict__ fw2, const float* __restrict__ fb2,
        const float* __restrict__ fw3, const float* __restrict__ fb3,
        float* __restrict__ out) {
    __shared__ __align__(16) __half s_w2t[32 * 40];     // [out 32][k 32 pad 40]
    __shared__ __align__(16) __half s_fw1t[64 * 40];    // [out 64][k 32 pad 40]
    __shared__ __align__(16) __half s_fw2t[128 * 72];   // [out 128][k 64 pad 72]

    const int tid = threadIdx.x;
    for (int i = tid; i < 1024; i += 256) {
        int o = i & 31, k = i >> 5;
        float v = (k < 16) ? w2n[k * 32 + o] : w2r[(k - 16) * 32 + o];
        s_w2t[o * 40 + k] = __float2half(v);
    }
    for (int i = tid; i < 2048; i += 256) {
        int o = i & 63, k = i >> 6;
        s_fw1t[o * 40 + k] = __float2half(fw1[k * 64 + o]);
    }
    for (int i = tid; i < 8192; i += 256) {
        int o = i & 127, k = i >> 7;
        s_fw2t[o * 72 + k] = __float2half(fw2[k * 128 + o]);
    }
    __syncthreads();

    const int l = tid & 63, li = l & 15, g = l >> 4;
    const int wid = tid >> 6;
    const int node = blockIdx.x * 64 + wid * 16 + li;
    const int nodec = node < N_NODES ? node : N_NODES - 1;
    const int sl0 = li + 32 * (g & 1), sl1 = sl0 + 16;
    const int tsel = g >> 1;

    H8 Bz;
    {
        const __half* zb = (g < 2) ? agg2 : h1;
        Bz.v = *(const uint4*)(zb + (nodec << 4) + ((g & 1) << 3));
    }

    // h2 = relu(z @ W2cat + b2): 2 M-tiles, K=32
    unsigned int p01[2], p23[2];
#pragma unroll
    for (int t = 0; t < 2; ++t) {
        f32x4 c = *(const f32x4*)(b2 + 16 * t + 4 * g);
        H8 A; A.v = *(const uint4*)(s_w2t + (16 * t + li) * 40 + 8 * g);
        c = MM(A, Bz, c);
        p01[t] = pkh(fmaxf(c[0], 0.f), fmaxf(c[1], 0.f));
        p23[t] = pkh(fmaxf(c[2], 0.f), fmaxf(c[3], 0.f));
    }
    H8 Bh2;
    {
        unsigned int a, b;
        a = __shfl((int)p01[0], sl0); b = __shfl((int)p01[1], sl0); Bh2.u[0] = tsel ? b : a;
        a = __shfl((int)p23[0], sl0); b = __shfl((int)p23[1], sl0); Bh2.u[1] = tsel ? b : a;
        a = __shfl((int)p01[0], sl1); b = __shfl((int)p01[1], sl1); Bh2.u[2] = tsel ? b : a;
        a = __shfl((int)p23[0], sl1); b = __shfl((int)p23[1], sl1); Bh2.u[3] = tsel ? b : a;
    }

    // h3 = relu(h2 @ fw1 + fb1): 4 M-tiles, K=32
    unsigned int q01[4], q23[4];
#pragma unroll
    for (int t = 0; t < 4; ++t) {
        f32x4 c = *(const f32x4*)(fb1 + 16 * t + 4 * g);
        H8 A; A.v = *(const uint4*)(s_fw1t + (16 * t + li) * 40 + 8 * g);
        c = MM(A, Bh2, c);
        q01[t] = pkh(fmaxf(c[0], 0.f), fmaxf(c[1], 0.f));
        q23[t] = pkh(fmaxf(c[2], 0.f), fmaxf(c[3], 0.f));
    }
    H8 Bh3[2];
#pragma unroll
    for (int s = 0; s < 2; ++s) {
        unsigned int a, b;
        a = __shfl((int)q01[2 * s], sl0); b = __shfl((int)q01[2 * s + 1], sl0); Bh3[s].u[0] = tsel ? b : a;
        a = __shfl((int)q23[2 * s], sl0); b = __shfl((int)q23[2 * s + 1], sl0); Bh3[s].u[1] = tsel ? b : a;
        a = __shfl((int)q01[2 * s], sl1); b = __shfl((int)q01[2 * s + 1], sl1); Bh3[s].u[2] = tsel ? b : a;
        a = __shfl((int)q23[2 * s], sl1); b = __shfl((int)q23[2 * s + 1], sl1); Bh3[s].u[3] = tsel ? b : a;
    }

    // h4 = relu(h3 @ fw2 + fb2); out = h4 @ fw3: 8 M-tiles, K=64
    float o0 = 0.f, o1 = 0.f;
#pragma unroll
    for (int m = 0; m < 8; ++m) {
        f32x4 c = *(const f32x4*)(fb2 + 16 * m + 4 * g);
        H8 A;
        A.v = *(const uint4*)(s_fw2t + (16 * m + li) * 72 + 8 * g);
        c = MM(A, Bh3[0], c);
        A.v = *(const uint4*)(s_fw2t + (16 * m + li) * 72 + 32 + 8 * g);
        c = MM(A, Bh3[1], c);
        const float4* wp = (const float4*)(fw3 + (16 * m + 4 * g) * 2);
        float4 wA = wp[0], wB = wp[1];
        float r0 = fmaxf(c[0], 0.f), r1 = fmaxf(c[1], 0.f);
        float r2 = fmaxf(c[2], 0.f), r3 = fmaxf(c[3], 0.f);
        o0 += r0 * wA.x + r1 * wA.z + r2 * wB.x + r3 * wB.z;
        o1 += r0 * wA.y + r1 * wA.w + r2 * wB.y + r3 * wB.w;
    }
    o0 += __shfl_xor(o0, 16); o0 += __shfl_xor(o0, 32);
    o1 += __shfl_xor(o1, 16); o1 += __shfl_xor(o1, 32);
    if (g == 0 && node < N_NODES) {
        float2 r; r.x = o0 + fb3[0]; r.y = o1 + fb3[1];
        *(float2*)(out + node * 2) = r;
    }
}

extern "C" void kernel_launch(void* const* d_in, const int* in_sizes, int n_in,
                              void* d_out, int out_size, void* d_ws, size_t ws_size,
                              hipStream_t stream) {
    const float* x   = (const float*)d_in[0];
    const int*   ei  = (const int*)d_in[1];
    const int*   src = ei;
    const int*   dst = ei + N_EDGES;
    const float* w1n = (const float*)d_in[2];
    const float* w1r = (const float*)d_in[3];
    const float* b1  = (const float*)d_in[4];
    const float* w2n = (const float*)d_in[5];
    const float* w2r = (const float*)d_in[6];
    const float* b2  = (const float*)d_in[7];
    const float* fw1 = (const float*)d_in[8];
    const float* fb1 = (const float*)d_in[9];
    const float* fw2 = (const float*)d_in[10];
    const float* fb2 = (const float*)d_in[11];
    const float* fw3 = (const float*)d_in[12];
    const float* fb3 = (const float*)d_in[13];
    float* out = (float*)d_out;

    // workspace layout (~20 MB)
    unsigned int* staging   = (unsigned int*)d_ws;                   // 391*4096 (6.4MB)
    int*          bucketCnt = (int*)(staging + NBUCKET * BCAP);      // 391
    unsigned int* nbrU      = (unsigned int*)(bucketCnt + NBUCKET);  // 50000*32 (6.4MB)
    int*          deg       = (int*)(nbrU + N_NODES * 32);           // 50000
    __half*       xw1n      = (__half*)(deg + N_NODES);              // 800000
    __half*       xr1b      = xw1n + N_EDGES;                        // 800000
    __half*       h1        = xr1b + N_EDGES;                        // 800000
    __half*       agg2      = h1 + N_EDGES;                          // 800000

    const unsigned short* nbr = (const unsigned short*)nbrU;

    hipMemsetAsync(bucketCnt, 0, NBUCKET * sizeof(int), stream);

    k_scat_lin1<<<NSCB + LIN1B, 256, 0, stream>>>(src, dst, bucketCnt, staging,
                                                  x, w1n, w1r, b1, xw1n, xr1b);
    k_buildAgg1<<<NBUCKET, 256, 0, stream>>>(staging, bucketCnt, xw1n, xr1b,
                                             nbrU, deg, h1);
    k_agg2<<<(N_NODES * 8 + 255) / 256, 256, 0, stream>>>(h1, deg, nbr, agg2);
    k_head<<<(N_NODES + 63) / 64, 256, 0, stream>>>(h1, agg2, w2n, w2r, b2,
                                                    fw1, fb1, fw2, fb2, fw3, fb3, out);
}

// Round 13
// 68.471 us; speedup vs baseline: 1.1230x; 1.1230x over previous
//
#include <hip/hip_runtime.h>
#include <hip/hip_fp16.h>

#define N_NODES 50000
#define N_EDGES 800000
#define MAXD 64
#define BSHIFT 7                        // 128 nodes per bucket
#define BNODES 128
#define NBUCKET 391                     // ceil(50000/128)
#define NSCB 128                        // scatter blocks
#define EPB (N_EDGES / NSCB)            // 6250 edges per scatter block
#define RCAP 64                         // slots per (block,bucket) run (mean 16)
#define LIN1B ((N_NODES + 63) / 64)     // 782 lin1 blocks

typedef _Float16 f16x8 __attribute__((ext_vector_type(8)));
typedef float f32x4 __attribute__((ext_vector_type(4)));

union H8 { uint4 v; unsigned int u[4]; f16x8 h; };

__device__ __forceinline__ f32x4 MM(const H8& a, const H8& b, f32x4 c) {
    return __builtin_amdgcn_mfma_f32_16x16x32_f16(a.h, b.h, c, 0, 0, 0);
}
__device__ __forceinline__ unsigned int pkh(float a, float b) {
    __half2 h = __floats2half2_rn(a, b);
    unsigned int u;
    __builtin_memcpy(&u, &h, 4);
    return u;
}

// ---- K1 (fused roles): blocks [0,NSCB) scatter edges into fixed
// per-(block,bucket) runs (no atomics, no memset, no write-amp);
// blocks [NSCB, NSCB+LIN1B) do MFMA lin1. ----
__global__ __launch_bounds__(256) void k_scat_lin1(
        const int* __restrict__ src, const int* __restrict__ dst,
        unsigned int* __restrict__ staging, int* __restrict__ counts,
        const float* __restrict__ x,
        const float* __restrict__ w1n, const float* __restrict__ w1r,
        const float* __restrict__ b1,
        __half* __restrict__ xw1n, __half* __restrict__ xr1b) {
    __shared__ __align__(16) unsigned char smem[4608];
    const int tid = threadIdx.x;

    if (blockIdx.x < NSCB) {
        // ---------- scatter role: single pass, LDS cursors ----------
        int* lh = (int*)smem;                      // [NBUCKET]
        for (int i = tid; i < NBUCKET; i += 256) lh[i] = 0;
        __syncthreads();
        const int sb = blockIdx.x;
        const int base = sb * EPB;
        for (int i = tid; i < EPB; i += 256) {
            int d = dst[base + i], s = src[base + i];
            int b = d >> BSHIFT;
            int pos = atomicAdd(&lh[b], 1);        // LDS atomic
            if (pos < RCAP)
                staging[(b * NSCB + sb) * RCAP + pos] =
                    ((unsigned int)(d & (BNODES - 1)) << 16) | (unsigned int)s;
        }
        __syncthreads();
        for (int i = tid; i < NBUCKET; i += 256)
            counts[i * NSCB + sb] = min(lh[i], RCAP);
    } else {
        // ---------- lin1 role (MFMA): wave = 16 nodes ----------
        __half* s_w1t = (__half*)smem;             // [out 32][k 64 pad 72]
        for (int i = tid; i < 2048; i += 256) {
            int o = i & 31, k = i >> 5;
            float v = (o < 16) ? w1n[k * 16 + o] : w1r[k * 16 + (o - 16)];
            s_w1t[o * 72 + k] = __float2half(v);
        }
        __syncthreads();
        const int l = tid & 63, li = l & 15, g = l >> 4;
        const int wid = tid >> 6;
        const int node = (blockIdx.x - NSCB) * 64 + wid * 16 + li;
        const int nodec = node < N_NODES ? node : N_NODES - 1;

        H8 B0, B1;
        {
            const float4* xp = (const float4*)(x + nodec * 64 + 8 * g);
            float4 v0 = xp[0], v1 = xp[1];
            B0.u[0] = pkh(v0.x, v0.y); B0.u[1] = pkh(v0.z, v0.w);
            B0.u[2] = pkh(v1.x, v1.y); B0.u[3] = pkh(v1.z, v1.w);
            const float4* xq = (const float4*)(x + nodec * 64 + 32 + 8 * g);
            float4 w0 = xq[0], w1 = xq[1];
            B1.u[0] = pkh(w0.x, w0.y); B1.u[1] = pkh(w0.z, w0.w);
            B1.u[2] = pkh(w1.x, w1.y); B1.u[3] = pkh(w1.z, w1.w);
        }
        H8 A;
        f32x4 c0 = {0.f, 0.f, 0.f, 0.f};                   // -> xw1n
        A.v = *(const uint4*)(s_w1t + li * 72 + 8 * g);
        c0 = MM(A, B0, c0);
        A.v = *(const uint4*)(s_w1t + li * 72 + 32 + 8 * g);
        c0 = MM(A, B1, c0);
        f32x4 c1 = *(const f32x4*)(b1 + 4 * g);            // -> xr1b (+b1)
        A.v = *(const uint4*)(s_w1t + (16 + li) * 72 + 8 * g);
        c1 = MM(A, B0, c1);
        A.v = *(const uint4*)(s_w1t + (16 + li) * 72 + 32 + 8 * g);
        c1 = MM(A, B1, c1);

        if (node < N_NODES) {
            uint2 s0, s1;
            s0.x = pkh(c0[0], c0[1]); s0.y = pkh(c0[2], c0[3]);
            s1.x = pkh(c1[0], c1[1]); s1.y = pkh(c1[2], c1[3]);
            *(uint2*)(xw1n + node * 16 + 4 * g) = s0;
            *(uint2*)(xr1b + node * 16 + 4 * g) = s1;
        }
    }
}

// ---- K2: per-bucket padded-table assembly from 128 runs ----
__global__ __launch_bounds__(256) void k_build(
        const unsigned int* __restrict__ staging, const int* __restrict__ counts,
        unsigned int* __restrict__ nbrU, int* __restrict__ deg) {
    __shared__ unsigned short ltbl[BNODES * MAXD];    // 16KB
    __shared__ int lcnt[BNODES];
    __shared__ int lc[NSCB];
    const int tid = threadIdx.x, b = blockIdx.x;
    if (tid < BNODES) lcnt[tid] = 0;
    for (int i = tid; i < NSCB; i += 256) lc[i] = counts[b * NSCB + i];
    __syncthreads();
    for (int i = tid; i < NSCB * RCAP; i += 256) {
        int sb = i >> 6, j = i & 63;
        if (j < lc[sb]) {
            unsigned int u = staging[(b * NSCB + sb) * RCAP + j];
            int dl = u >> 16, s = u & 0xFFFF;
            int slot = atomicAdd(&lcnt[dl], 1);
            if (slot < MAXD) ltbl[(dl << 6) + slot] = (unsigned short)s;
        }
    }
    __syncthreads();
    const int nbase = b << BSHIFT;
    for (int i = tid; i < BNODES * 32; i += 256) {
        int nl = i >> 5, j = i & 31;
        int node = nbase + nl;
        if (node < N_NODES && 2 * j < lcnt[nl]) {
            unsigned int lo = ltbl[(nl << 6) + 2 * j];
            unsigned int hi = ltbl[(nl << 6) + 2 * j + 1];
            nbrU[(node << 5) + j] = lo | (hi << 16);
        }
    }
    if (tid < BNODES && nbase + tid < N_NODES) deg[nbase + tid] = lcnt[tid];
}

// ---- K3: h1 = relu(mean_nbrs(xw1n) + xr1b)  (half2 lanes: 8 thr/node) ----
__global__ __launch_bounds__(256) void k_agg1(
        const __half* __restrict__ xw1n, const __half* __restrict__ xr1b,
        const int* __restrict__ deg, const unsigned short* __restrict__ nbr,
        __half* __restrict__ h1) {
    const int t = blockIdx.x * 256 + threadIdx.x;
    if (t >= N_NODES * 8) return;
    const int node = t >> 3, fp = t & 7;
    int c = deg[node];
    float inv = c > 0 ? 1.f / (float)c : 1.f;
    int cc = c > MAXD ? MAXD : c;
    const unsigned short* np = nbr + (node << 6);
    float2 a0 = {0.f, 0.f}, a1 = {0.f, 0.f}, a2 = {0.f, 0.f}, a3 = {0.f, 0.f};
    int j = 0;
    for (; j + 4 <= cc; j += 4) {
        float2 v0 = __half22float2(*(const __half2*)(xw1n + (np[j + 0] << 4) + (fp << 1)));
        float2 v1 = __half22float2(*(const __half2*)(xw1n + (np[j + 1] << 4) + (fp << 1)));
        float2 v2 = __half22float2(*(const __half2*)(xw1n + (np[j + 2] << 4) + (fp << 1)));
        float2 v3 = __half22float2(*(const __half2*)(xw1n + (np[j + 3] << 4) + (fp << 1)));
        a0.x += v0.x; a0.y += v0.y; a1.x += v1.x; a1.y += v1.y;
        a2.x += v2.x; a2.y += v2.y; a3.x += v3.x; a3.y += v3.y;
    }
    for (; j < cc; ++j) {
        float2 v = __half22float2(*(const __half2*)(xw1n + (np[j] << 4) + (fp << 1)));
        a0.x += v.x; a0.y += v.y;
    }
    float2 r = __half22float2(*(const __half2*)(xr1b + (node << 4) + (fp << 1)));
    float rx = fmaxf((a0.x + a1.x + a2.x + a3.x) * inv + r.x, 0.f);
    float ry = fmaxf((a0.y + a1.y + a2.y + a3.y) * inv + r.y, 0.f);
    *(__half2*)(h1 + (node << 4) + (fp << 1)) = __floats2half2_rn(rx, ry);
}

// ---- K4 (k_head, MFMA): inline agg2 gather + SAGE2 + MLP head ----
// wave = 16 nodes. Gather: lane l sums h1 feats 4*(l&3)..+4 of node (l>>2);
// 4-shfl in-wave transpose lands it directly in the B-frag layout
// (k = (lane>>4)*8 + e, col = lane&15), same mapping round 11 verified.
__global__ __launch_bounds__(256) void k_head(
        const __half* __restrict__ h1,
        const int* __restrict__ deg, const unsigned short* __restrict__ nbr,
        const float* __restrict__ w2n, const float* __restrict__ w2r,
        const float* __restrict__ b2,
        const float* __restrict__ fw1, const float* __restrict__ fb1,
        const float* __restrict__ fw2, const float* __restrict__ fb2,
        const float* __restrict__ fw3, const float* __restrict__ fb3,
        float* __restrict__ out) {
    __shared__ __align__(16) __half s_w2t[32 * 40];     // [out 32][k 32 pad 40]
    __shared__ __align__(16) __half s_fw1t[64 * 40];    // [out 64][k 32 pad 40]
    __shared__ __align__(16) __half s_fw2t[128 * 72];   // [out 128][k 64 pad 72]

    const int tid = threadIdx.x;
    for (int i = tid; i < 1024; i += 256) {
        int o = i & 31, k = i >> 5;
        float v = (k < 16) ? w2n[k * 32 + o] : w2r[(k - 16) * 32 + o];
        s_w2t[o * 40 + k] = __float2half(v);
    }
    for (int i = tid; i < 2048; i += 256) {
        int o = i & 63, k = i >> 6;
        s_fw1t[o * 40 + k] = __float2half(fw1[k * 64 + o]);
    }
    for (int i = tid; i < 8192; i += 256) {
        int o = i & 127, k = i >> 7;
        s_fw2t[o * 72 + k] = __float2half(fw2[k * 128 + o]);
    }
    __syncthreads();

    const int l = tid & 63, li = l & 15, g = l >> 4;
    const int wid = tid >> 6;
    const int nbase = blockIdx.x * 64 + wid * 16;
    const int node = nbase + li;
    const int nodec = node < N_NODES ? node : N_NODES - 1;
    const int sl0 = li + 32 * (g & 1), sl1 = sl0 + 16;
    const int tsel = g >> 1;

    // ---- inline agg2 gather (all 64 lanes) ----
    unsigned int ua0, ua1;
    {
        const int gnode = nbase + (l >> 2);
        const int gn = gnode < N_NODES ? gnode : N_NODES - 1;
        int c = deg[gn];
        float inv = c > 0 ? 1.f / (float)c : 1.f;
        int cc = c > MAXD ? MAXD : c;
        const unsigned short* np = nbr + (gn << 6);
        const int fo = (l & 3) << 2;                     // feat offset 0/4/8/12
        float ax = 0.f, ay = 0.f, az = 0.f, aw = 0.f;
        int j = 0;
        for (; j + 2 <= cc; j += 2) {
            const __half2* h0 = (const __half2*)(h1 + (np[j] << 4) + fo);
            const __half2* h1p = (const __half2*)(h1 + (np[j + 1] << 4) + fo);
            float2 v0 = __half22float2(h0[0]), v1 = __half22float2(h0[1]);
            float2 w0 = __half22float2(h1p[0]), w1 = __half22float2(h1p[1]);
            ax += v0.x + w0.x; ay += v0.y + w0.y;
            az += v1.x + w1.x; aw += v1.y + w1.y;
        }
        if (j < cc) {
            const __half2* h0 = (const __half2*)(h1 + (np[j] << 4) + fo);
            float2 v0 = __half22float2(h0[0]), v1 = __half22float2(h0[1]);
            ax += v0.x; ay += v0.y; az += v1.x; aw += v1.y;
        }
        ua0 = pkh(ax * inv, ay * inv);
        ua1 = pkh(az * inv, aw * inv);
    }
    // transpose into B-frag: lane (li,g<2) gets agg2[li][8g..8g+7]
    H8 Bz;
    {
        const int sl = (li << 2) + ((g & 1) << 1);
        Bz.u[0] = (unsigned int)__shfl((int)ua0, sl);
        Bz.u[1] = (unsigned int)__shfl((int)ua1, sl);
        Bz.u[2] = (unsigned int)__shfl((int)ua0, sl + 1);
        Bz.u[3] = (unsigned int)__shfl((int)ua1, sl + 1);
        if (g >= 2)                                      // k>=16 -> h1 direct
            Bz.v = *(const uint4*)(h1 + (nodec << 4) + ((g & 1) << 3));
    }

    // ---- h2 = relu(z @ W2cat + b2): 2 M-tiles, K=32 ----
    unsigned int p01[2], p23[2];
#pragma unroll
    for (int t = 0; t < 2; ++t) {
        f32x4 c = *(const f32x4*)(b2 + 16 * t + 4 * g);
        H8 A; A.v = *(const uint4*)(s_w2t + (16 * t + li) * 40 + 8 * g);
        c = MM(A, Bz, c);
        p01[t] = pkh(fmaxf(c[0], 0.f), fmaxf(c[1], 0.f));
        p23[t] = pkh(fmaxf(c[2], 0.f), fmaxf(c[3], 0.f));
    }
    H8 Bh2;
    {
        unsigned int a, b;
        a = __shfl((int)p01[0], sl0); b = __shfl((int)p01[1], sl0); Bh2.u[0] = tsel ? b : a;
        a = __shfl((int)p23[0], sl0); b = __shfl((int)p23[1], sl0); Bh2.u[1] = tsel ? b : a;
        a = __shfl((int)p01[0], sl1); b = __shfl((int)p01[1], sl1); Bh2.u[2] = tsel ? b : a;
        a = __shfl((int)p23[0], sl1); b = __shfl((int)p23[1], sl1); Bh2.u[3] = tsel ? b : a;
    }

    // ---- h3 = relu(h2 @ fw1 + fb1): 4 M-tiles, K=32 ----
    unsigned int q01[4], q23[4];
#pragma unroll
    for (int t = 0; t < 4; ++t) {
        f32x4 c = *(const f32x4*)(fb1 + 16 * t + 4 * g);
        H8 A; A.v = *(const uint4*)(s_fw1t + (16 * t + li) * 40 + 8 * g);
        c = MM(A, Bh2, c);
        q01[t] = pkh(fmaxf(c[0], 0.f), fmaxf(c[1], 0.f));
        q23[t] = pkh(fmaxf(c[2], 0.f), fmaxf(c[3], 0.f));
    }
    H8 Bh3[2];
#pragma unroll
    for (int s = 0; s < 2; ++s) {
        unsigned int a, b;
        a = __shfl((int)q01[2 * s], sl0); b = __shfl((int)q01[2 * s + 1], sl0); Bh3[s].u[0] = tsel ? b : a;
        a = __shfl((int)q23[2 * s], sl0); b = __shfl((int)q23[2 * s + 1], sl0); Bh3[s].u[1] = tsel ? b : a;
        a = __shfl((int)q01[2 * s], sl1); b = __shfl((int)q01[2 * s + 1], sl1); Bh3[s].u[2] = tsel ? b : a;
        a = __shfl((int)q23[2 * s], sl1); b = __shfl((int)q23[2 * s + 1], sl1); Bh3[s].u[3] = tsel ? b : a;
    }

    // ---- h4 = relu(h3 @ fw2 + fb2); out = h4 @ fw3: 8 M-tiles, K=64 ----
    float o0 = 0.f, o1 = 0.f;
#pragma unroll
    for (int m = 0; m < 8; ++m) {
        f32x4 c = *(const f32x4*)(fb2 + 16 * m + 4 * g);
        H8 A;
        A.v = *(const uint4*)(s_fw2t + (16 * m + li) * 72 + 8 * g);
        c = MM(A, Bh3[0], c);
        A.v = *(const uint4*)(s_fw2t + (16 * m + li) * 72 + 32 + 8 * g);
        c = MM(A, Bh3[1], c);
        const float4* wp = (const float4*)(fw3 + (16 * m + 4 * g) * 2);
        float4 wA = wp[0], wB = wp[1];
        float r0 = fmaxf(c[0], 0.f), r1 = fmaxf(c[1], 0.f);
        float r2 = fmaxf(c[2], 0.f), r3 = fmaxf(c[3], 0.f);
        o0 += r0 * wA.x + r1 * wA.z + r2 * wB.x + r3 * wB.z;
        o1 += r0 * wA.y + r1 * wA.w + r2 * wB.y + r3 * wB.w;
    }
    o0 += __shfl_xor(o0, 16); o0 += __shfl_xor(o0, 32);
    o1 += __shfl_xor(o1, 16); o1 += __shfl_xor(o1, 32);
    if (g == 0 && node < N_NODES) {
        float2 r; r.x = o0 + fb3[0]; r.y = o1 + fb3[1];
        *(float2*)(out + node * 2) = r;
    }
}

extern "C" void kernel_launch(void* const* d_in, const int* in_sizes, int n_in,
                              void* d_out, int out_size, void* d_ws, size_t ws_size,
                              hipStream_t stream) {
    const float* x   = (const float*)d_in[0];
    const int*   ei  = (const int*)d_in[1];
    const int*   src = ei;
    const int*   dst = ei + N_EDGES;
    const float* w1n = (const float*)d_in[2];
    const float* w1r = (const float*)d_in[3];
    const float* b1  = (const float*)d_in[4];
    const float* w2n = (const float*)d_in[5];
    const float* w2r = (const float*)d_in[6];
    const float* b2  = (const float*)d_in[7];
    const float* fw1 = (const float*)d_in[8];
    const float* fb1 = (const float*)d_in[9];
    const float* fw2 = (const float*)d_in[10];
    const float* fb2 = (const float*)d_in[11];
    const float* fw3 = (const float*)d_in[12];
    const float* fb3 = (const float*)d_in[13];
    float* out = (float*)d_out;

    // workspace (~25 MB); every consumed cell is freshly written each call
    unsigned int* staging = (unsigned int*)d_ws;                 // 391*128*64 (12.8MB)
    int*          counts  = (int*)(staging + NBUCKET * NSCB * RCAP); // 50048
    unsigned int* nbrU    = (unsigned int*)(counts + NBUCKET * NSCB); // 50000*32 (6.4MB)
    int*          deg     = (int*)(nbrU + N_NODES * 32);         // 50000
    __half*       xw1n    = (__half*)(deg + N_NODES);            // 800000
    __half*       xr1b    = xw1n + N_EDGES;                      // 800000
    __half*       h1      = xr1b + N_EDGES;                      // 800000

    const unsigned short* nbr = (const unsigned short*)nbrU;

    k_scat_lin1<<<NSCB + LIN1B, 256, 0, stream>>>(src, dst, staging, counts,
                                                  x, w1n, w1r, b1, xw1n, xr1b);
    k_build<<<NBUCKET, 256, 0, stream>>>(staging, counts, nbrU, deg);
    k_agg1<<<(N_NODES * 8 + 255) / 256, 256, 0, stream>>>(xw1n, xr1b, deg, nbr, h1);
    k_head<<<(N_NODES + 63) / 64, 256, 0, stream>>>(h1, deg, nbr, w2n, w2r, b2,
                                                    fw1, fb1, fw2, fb2, fw3, fb3, out);
}

// Round 14
// 63.838 us; speedup vs baseline: 1.2045x; 1.0726x over previous
//
#include <hip/hip_runtime.h>
#include <hip/hip_fp16.h>

#define N_NODES 50000
#define N_EDGES 800000
#define MAXD 64
#define BSHIFT 6                        // 64 nodes per bucket
#define BNODES 64
#define NBUCKET 782                     // ceil(50000/64)
#define NSCB 128                        // scatter blocks
#define EPB (N_EDGES / NSCB)            // 6250 edges per scatter block
#define RCAP 32                         // slots per (block,bucket) run (mean 8)
#define LIN1B ((N_NODES + 63) / 64)     // 782 lin1 blocks

typedef _Float16 f16x8 __attribute__((ext_vector_type(8)));
typedef float f32x4 __attribute__((ext_vector_type(4)));

union H8 { uint4 v; unsigned int u[4]; f16x8 h; };

__device__ __forceinline__ f32x4 MM(const H8& a, const H8& b, f32x4 c) {
    return __builtin_amdgcn_mfma_f32_16x16x32_f16(a.h, b.h, c, 0, 0, 0);
}
__device__ __forceinline__ unsigned int pkh(float a, float b) {
    __half2 h = __floats2half2_rn(a, b);
    unsigned int u;
    __builtin_memcpy(&u, &h, 4);
    return u;
}

// ---- K1 (fused roles): blocks [0,NSCB) scatter edges into fixed
// per-(block,bucket) runs; blocks [NSCB, NSCB+LIN1B) do MFMA lin1. ----
__global__ __launch_bounds__(256) void k_scat_lin1(
        const int* __restrict__ src, const int* __restrict__ dst,
        unsigned int* __restrict__ staging, int* __restrict__ counts,
        const float* __restrict__ x,
        const float* __restrict__ w1n, const float* __restrict__ w1r,
        const float* __restrict__ b1,
        __half* __restrict__ xw1n, __half* __restrict__ xr1b) {
    __shared__ __align__(16) unsigned char smem[4608];
    const int tid = threadIdx.x;

    if (blockIdx.x < NSCB) {
        // ---------- scatter role: single pass, LDS cursors ----------
        int* lh = (int*)smem;                      // [NBUCKET] = 3128B
        for (int i = tid; i < NBUCKET; i += 256) lh[i] = 0;
        __syncthreads();
        const int sb = blockIdx.x;
        const int base = sb * EPB;
        for (int i = tid; i < EPB; i += 256) {
            int d = dst[base + i], s = src[base + i];
            int b = d >> BSHIFT;
            int pos = atomicAdd(&lh[b], 1);        // LDS atomic
            if (pos < RCAP)
                staging[(b * NSCB + sb) * RCAP + pos] =
                    ((unsigned int)(d & (BNODES - 1)) << 16) | (unsigned int)s;
        }
        __syncthreads();
        for (int i = tid; i < NBUCKET; i += 256)
            counts[i * NSCB + sb] = min(lh[i], RCAP);
    } else {
        // ---------- lin1 role (MFMA): wave = 16 nodes ----------
        __half* s_w1t = (__half*)smem;             // [out 32][k 64 pad 72]
        for (int i = tid; i < 1024; i += 256) {    // pack pairs along k
            int o = i & 31, kp = i >> 5;
            const float* W = (o < 16) ? (w1n + o) : (w1r + (o - 16));
            *(unsigned int*)(s_w1t + o * 72 + 2 * kp) =
                pkh(W[(2 * kp) * 16], W[(2 * kp + 1) * 16]);
        }
        __syncthreads();
        const int l = tid & 63, li = l & 15, g = l >> 4;
        const int wid = tid >> 6;
        const int node = (blockIdx.x - NSCB) * 64 + wid * 16 + li;
        const int nodec = node < N_NODES ? node : N_NODES - 1;

        H8 B0, B1;
        {
            const float4* xp = (const float4*)(x + nodec * 64 + 8 * g);
            float4 v0 = xp[0], v1 = xp[1];
            B0.u[0] = pkh(v0.x, v0.y); B0.u[1] = pkh(v0.z, v0.w);
            B0.u[2] = pkh(v1.x, v1.y); B0.u[3] = pkh(v1.z, v1.w);
            const float4* xq = (const float4*)(x + nodec * 64 + 32 + 8 * g);
            float4 w0 = xq[0], w1 = xq[1];
            B1.u[0] = pkh(w0.x, w0.y); B1.u[1] = pkh(w0.z, w0.w);
            B1.u[2] = pkh(w1.x, w1.y); B1.u[3] = pkh(w1.z, w1.w);
        }
        H8 A;
        f32x4 c0 = {0.f, 0.f, 0.f, 0.f};                   // -> xw1n
        A.v = *(const uint4*)(s_w1t + li * 72 + 8 * g);
        c0 = MM(A, B0, c0);
        A.v = *(const uint4*)(s_w1t + li * 72 + 32 + 8 * g);
        c0 = MM(A, B1, c0);
        f32x4 c1 = *(const f32x4*)(b1 + 4 * g);            // -> xr1b (+b1)
        A.v = *(const uint4*)(s_w1t + (16 + li) * 72 + 8 * g);
        c1 = MM(A, B0, c1);
        A.v = *(const uint4*)(s_w1t + (16 + li) * 72 + 32 + 8 * g);
        c1 = MM(A, B1, c1);

        if (node < N_NODES) {
            uint2 s0, s1;
            s0.x = pkh(c0[0], c0[1]); s0.y = pkh(c0[2], c0[3]);
            s1.x = pkh(c1[0], c1[1]); s1.y = pkh(c1[2], c1[3]);
            *(uint2*)(xw1n + node * 16 + 4 * g) = s0;
            *(uint2*)(xr1b + node * 16 + 4 * g) = s1;
        }
    }
}

// ---- K2: per-bucket table assembly + fused agg1 (782 blocks, 64 nodes) ----
__global__ __launch_bounds__(256) void k_buildAgg1(
        const unsigned int* __restrict__ staging, const int* __restrict__ counts,
        const __half* __restrict__ xw1n, const __half* __restrict__ xr1b,
        unsigned int* __restrict__ nbrU, int* __restrict__ deg,
        __half* __restrict__ h1) {
    __shared__ unsigned short ltbl[BNODES * MAXD];    // 8KB
    __shared__ int lcnt[BNODES];
    __shared__ int lc[NSCB];
    const int tid = threadIdx.x, b = blockIdx.x;
    if (tid < BNODES) lcnt[tid] = 0;
    for (int i = tid; i < NSCB; i += 256) lc[i] = counts[b * NSCB + i];
    __syncthreads();
    for (int i = tid; i < NSCB * RCAP; i += 256) {    // 4096 slots
        int sb = i >> 5, j = i & 31;
        if (j < lc[sb]) {
            unsigned int u = staging[(b * NSCB + sb) * RCAP + j];
            int dl = u >> 16, s = u & 0xFFFF;
            int slot = atomicAdd(&lcnt[dl], 1);
            if (slot < MAXD) ltbl[(dl << 6) + slot] = (unsigned short)s;
        }
    }
    __syncthreads();
    const int nbase = b << BSHIFT;
    // packed table write (for k_head's gather) + deg
    for (int i = tid; i < BNODES * 32; i += 256) {
        int nl = i >> 5, j = i & 31;
        int node = nbase + nl;
        if (node < N_NODES && 2 * j < lcnt[nl]) {
            unsigned int lo = ltbl[(nl << 6) + 2 * j];
            unsigned int hi = ltbl[(nl << 6) + 2 * j + 1];
            nbrU[(node << 5) + j] = lo | (hi << 16);
        }
    }
    if (tid < BNODES && nbase + tid < N_NODES) deg[nbase + tid] = lcnt[tid];
    // fused agg1: h1 = relu(mean_nbrs(xw1n) + xr1b); 8 half2-lanes/node
    for (int i = tid; i < BNODES * 8; i += 256) {     // 512 items, 2/thread
        int nl = i >> 3, fp = i & 7;
        int node = nbase + nl;
        if (node >= N_NODES) continue;
        int c = lcnt[nl];
        float inv = c > 0 ? 1.f / (float)c : 1.f;
        int cc = c > MAXD ? MAXD : c;
        const unsigned short* np = ltbl + (nl << 6);  // LDS broadcast reads
        float2 a0 = {0.f, 0.f}, a1 = {0.f, 0.f}, a2 = {0.f, 0.f}, a3 = {0.f, 0.f};
        int j = 0;
        for (; j + 4 <= cc; j += 4) {
            float2 v0 = __half22float2(*(const __half2*)(xw1n + (np[j + 0] << 4) + (fp << 1)));
            float2 v1 = __half22float2(*(const __half2*)(xw1n + (np[j + 1] << 4) + (fp << 1)));
            float2 v2 = __half22float2(*(const __half2*)(xw1n + (np[j + 2] << 4) + (fp << 1)));
            float2 v3 = __half22float2(*(const __half2*)(xw1n + (np[j + 3] << 4) + (fp << 1)));
            a0.x += v0.x; a0.y += v0.y; a1.x += v1.x; a1.y += v1.y;
            a2.x += v2.x; a2.y += v2.y; a3.x += v3.x; a3.y += v3.y;
        }
        for (; j < cc; ++j) {
            float2 v = __half22float2(*(const __half2*)(xw1n + (np[j] << 4) + (fp << 1)));
            a0.x += v.x; a0.y += v.y;
        }
        float2 r = __half22float2(*(const __half2*)(xr1b + (node << 4) + (fp << 1)));
        float rx = fmaxf((a0.x + a1.x + a2.x + a3.x) * inv + r.x, 0.f);
        float ry = fmaxf((a0.y + a1.y + a2.y + a3.y) * inv + r.y, 0.f);
        *(__half2*)(h1 + (node << 4) + (fp << 1)) = __floats2half2_rn(rx, ry);
    }
}

// ---- K3 (k_head, MFMA): inline agg2 gather + SAGE2 + MLP head ----
// wave = 16 nodes; layout identical to round 13 (verified).
__global__ __launch_bounds__(256) void k_head(
        const __half* __restrict__ h1,
        const int* __restrict__ deg, const unsigned short* __restrict__ nbr,
        const float* __restrict__ w2n, const float* __restrict__ w2r,
        const float* __restrict__ b2,
        const float* __restrict__ fw1, const float* __restrict__ fb1,
        const float* __restrict__ fw2, const float* __restrict__ fb2,
        const float* __restrict__ fw3, const float* __restrict__ fb3,
        float* __restrict__ out) {
    __shared__ __align__(16) __half s_w2t[32 * 40];     // [out 32][k 32 pad 40]
    __shared__ __align__(16) __half s_fw1t[64 * 40];    // [out 64][k 32 pad 40]
    __shared__ __align__(16) __half s_fw2t[128 * 72];   // [out 128][k 64 pad 72]

    const int tid = threadIdx.x;
    for (int i = tid; i < 512; i += 256) {              // w2t: pairs along k
        int o = i & 31, kp = i >> 5;                    // kp 0..15
        const float* W = (kp < 8) ? (w2n + o) : (w2r + o - 8 * 2 * 32 + 0);
        float v0, v1;
        if (kp < 8) { v0 = w2n[(2 * kp) * 32 + o];      v1 = w2n[(2 * kp + 1) * 32 + o]; }
        else        { v0 = w2r[(2 * kp - 16) * 32 + o]; v1 = w2r[(2 * kp - 15) * 32 + o]; }
        (void)W;
        *(unsigned int*)(s_w2t + o * 40 + 2 * kp) = pkh(v0, v1);
    }
    for (int i = tid; i < 1024; i += 256) {             // fw1t: pairs along k
        int o = i & 63, kp = i >> 6;                    // kp 0..15
        *(unsigned int*)(s_fw1t + o * 40 + 2 * kp) =
            pkh(fw1[(2 * kp) * 64 + o], fw1[(2 * kp + 1) * 64 + o]);
    }
    for (int i = tid; i < 4096; i += 256) {             // fw2t: pairs along k
        int o = i & 127, kp = i >> 7;                   // kp 0..31
        *(unsigned int*)(s_fw2t + o * 72 + 2 * kp) =
            pkh(fw2[(2 * kp) * 128 + o], fw2[(2 * kp + 1) * 128 + o]);
    }
    __syncthreads();

    const int l = tid & 63, li = l & 15, g = l >> 4;
    const int wid = tid >> 6;
    const int nbase = blockIdx.x * 64 + wid * 16;
    const int node = nbase + li;
    const int nodec = node < N_NODES ? node : N_NODES - 1;
    const int sl0 = li + 32 * (g & 1), sl1 = sl0 + 16;
    const int tsel = g >> 1;

    // ---- inline agg2 gather (all 64 lanes) ----
    unsigned int ua0, ua1;
    {
        const int gnode = nbase + (l >> 2);
        const int gn = gnode < N_NODES ? gnode : N_NODES - 1;
        int c = deg[gn];
        float inv = c > 0 ? 1.f / (float)c : 1.f;
        int cc = c > MAXD ? MAXD : c;
        const unsigned short* np = nbr + (gn << 6);
        const int fo = (l & 3) << 2;                    // feat offset 0/4/8/12
        float ax = 0.f, ay = 0.f, az = 0.f, aw = 0.f;
        int j = 0;
        for (; j + 2 <= cc; j += 2) {
            const __half2* h0 = (const __half2*)(h1 + (np[j] << 4) + fo);
            const __half2* h1p = (const __half2*)(h1 + (np[j + 1] << 4) + fo);
            float2 v0 = __half22float2(h0[0]), v1 = __half22float2(h0[1]);
            float2 w0 = __half22float2(h1p[0]), w1 = __half22float2(h1p[1]);
            ax += v0.x + w0.x; ay += v0.y + w0.y;
            az += v1.x + w1.x; aw += v1.y + w1.y;
        }
        if (j < cc) {
            const __half2* h0 = (const __half2*)(h1 + (np[j] << 4) + fo);
            float2 v0 = __half22float2(h0[0]), v1 = __half22float2(h0[1]);
            ax += v0.x; ay += v0.y; az += v1.x; aw += v1.y;
        }
        ua0 = pkh(ax * inv, ay * inv);
        ua1 = pkh(az * inv, aw * inv);
    }
    // transpose into B-frag: lane (li,g<2) gets agg2[li][8g..8g+7]
    H8 Bz;
    {
        const int sl = (li << 2) + ((g & 1) << 1);
        Bz.u[0] = (unsigned int)__shfl((int)ua0, sl);
        Bz.u[1] = (unsigned int)__shfl((int)ua1, sl);
        Bz.u[2] = (unsigned int)__shfl((int)ua0, sl + 1);
        Bz.u[3] = (unsigned int)__shfl((int)ua1, sl + 1);
        if (g >= 2)                                     // k>=16 -> h1 direct
            Bz.v = *(const uint4*)(h1 + (nodec << 4) + ((g & 1) << 3));
    }

    // ---- h2 = relu(z @ W2cat + b2): 2 M-tiles, K=32 ----
    unsigned int p01[2], p23[2];
#pragma unroll
    for (int t = 0; t < 2; ++t) {
        f32x4 c = *(const f32x4*)(b2 + 16 * t + 4 * g);
        H8 A; A.v = *(const uint4*)(s_w2t + (16 * t + li) * 40 + 8 * g);
        c = MM(A, Bz, c);
        p01[t] = pkh(fmaxf(c[0], 0.f), fmaxf(c[1], 0.f));
        p23[t] = pkh(fmaxf(c[2], 0.f), fmaxf(c[3], 0.f));
    }
    H8 Bh2;
    {
        unsigned int a, b;
        a = __shfl((int)p01[0], sl0); b = __shfl((int)p01[1], sl0); Bh2.u[0] = tsel ? b : a;
        a = __shfl((int)p23[0], sl0); b = __shfl((int)p23[1], sl0); Bh2.u[1] = tsel ? b : a;
        a = __shfl((int)p01[0], sl1); b = __shfl((int)p01[1], sl1); Bh2.u[2] = tsel ? b : a;
        a = __shfl((int)p23[0], sl1); b = __shfl((int)p23[1], sl1); Bh2.u[3] = tsel ? b : a;
    }

    // ---- h3 = relu(h2 @ fw1 + fb1): 4 M-tiles, K=32 ----
    unsigned int q01[4], q23[4];
#pragma unroll
    for (int t = 0; t < 4; ++t) {
        f32x4 c = *(const f32x4*)(fb1 + 16 * t + 4 * g);
        H8 A; A.v = *(const uint4*)(s_fw1t + (16 * t + li) * 40 + 8 * g);
        c = MM(A, Bh2, c);
        q01[t] = pkh(fmaxf(c[0], 0.f), fmaxf(c[1], 0.f));
        q23[t] = pkh(fmaxf(c[2], 0.f), fmaxf(c[3], 0.f));
    }
    H8 Bh3[2];
#pragma unroll
    for (int s = 0; s < 2; ++s) {
        unsigned int a, b;
        a = __shfl((int)q01[2 * s], sl0); b = __shfl((int)q01[2 * s + 1], sl0); Bh3[s].u[0] = tsel ? b : a;
        a = __shfl((int)q23[2 * s], sl0); b = __shfl((int)q23[2 * s + 1], sl0); Bh3[s].u[1] = tsel ? b : a;
        a = __shfl((int)q01[2 * s], sl1); b = __shfl((int)q01[2 * s + 1], sl1); Bh3[s].u[2] = tsel ? b : a;
        a = __shfl((int)q23[2 * s], sl1); b = __shfl((int)q23[2 * s + 1], sl1); Bh3[s].u[3] = tsel ? b : a;
    }

    // ---- h4 = relu(h3 @ fw2 + fb2); out = h4 @ fw3: 8 M-tiles, K=64 ----
    float o0 = 0.f, o1 = 0.f;
#pragma unroll
    for (int m = 0; m < 8; ++m) {
        f32x4 c = *(const f32x4*)(fb2 + 16 * m + 4 * g);
        H8 A;
        A.v = *(const uint4*)(s_fw2t + (16 * m + li) * 72 + 8 * g);
        c = MM(A, Bh3[0], c);
        A.v = *(const uint4*)(s_fw2t + (16 * m + li) * 72 + 32 + 8 * g);
        c = MM(A, Bh3[1], c);
        const float4* wp = (const float4*)(fw3 + (16 * m + 4 * g) * 2);
        float4 wA = wp[0], wB = wp[1];
        float r0 = fmaxf(c[0], 0.f), r1 = fmaxf(c[1], 0.f);
        float r2 = fmaxf(c[2], 0.f), r3 = fmaxf(c[3], 0.f);
        o0 += r0 * wA.x + r1 * wA.z + r2 * wB.x + r3 * wB.z;
        o1 += r0 * wA.y + r1 * wA.w + r2 * wB.y + r3 * wB.w;
    }
    o0 += __shfl_xor(o0, 16); o0 += __shfl_xor(o0, 32);
    o1 += __shfl_xor(o1, 16); o1 += __shfl_xor(o1, 32);
    if (g == 0 && node < N_NODES) {
        float2 r; r.x = o0 + fb3[0]; r.y = o1 + fb3[1];
        *(float2*)(out + node * 2) = r;
    }
}

extern "C" void kernel_launch(void* const* d_in, const int* in_sizes, int n_in,
                              void* d_out, int out_size, void* d_ws, size_t ws_size,
                              hipStream_t stream) {
    const float* x   = (const float*)d_in[0];
    const int*   ei  = (const int*)d_in[1];
    const int*   src = ei;
    const int*   dst = ei + N_EDGES;
    const float* w1n = (const float*)d_in[2];
    const float* w1r = (const float*)d_in[3];
    const float* b1  = (const float*)d_in[4];
    const float* w2n = (const float*)d_in[5];
    const float* w2r = (const float*)d_in[6];
    const float* b2  = (const float*)d_in[7];
    const float* fw1 = (const float*)d_in[8];
    const float* fb1 = (const float*)d_in[9];
    const float* fw2 = (const float*)d_in[10];
    const float* fb2 = (const float*)d_in[11];
    const float* fw3 = (const float*)d_in[12];
    const float* fb3 = (const float*)d_in[13];
    float* out = (float*)d_out;

    // workspace (~24.6 MB); every consumed cell is freshly written each call
    unsigned int* staging = (unsigned int*)d_ws;                     // 782*128*32 (12.8MB)
    int*          counts  = (int*)(staging + NBUCKET * NSCB * RCAP); // 100096
    unsigned int* nbrU    = (unsigned int*)(counts + NBUCKET * NSCB);// 50000*32 (6.4MB)
    int*          deg     = (int*)(nbrU + N_NODES * 32);             // 50000
    __half*       xw1n    = (__half*)(deg + N_NODES);                // 800000
    __half*       xr1b    = xw1n + N_EDGES;                          // 800000
    __half*       h1      = xr1b + N_EDGES;                          // 800000

    const unsigned short* nbr = (const unsigned short*)nbrU;

    k_scat_lin1<<<NSCB + LIN1B, 256, 0, stream>>>(src, dst, staging, counts,
                                                  x, w1n, w1r, b1, xw1n, xr1b);
    k_buildAgg1<<<NBUCKET, 256, 0, stream>>>(staging, counts, xw1n, xr1b,
                                             nbrU, deg, h1);
    k_head<<<(N_NODES + 63) / 64, 256, 0, stream>>>(h1, deg, nbr, w2n, w2r, b2,
                                                    fw1, fb1, fw2, fb2, fw3, fb3, out);
}

// Round 15
// 59.818 us; speedup vs baseline: 1.2855x; 1.0672x over previous
//
#include <hip/hip_runtime.h>
#include <hip/hip_fp16.h>

#define N_NODES 50000
#define N_EDGES 800000
#define MAXD 64
#define BSHIFT 6                        // 64 nodes per bucket
#define BNODES 64
#define NBUCKET 782                     // ceil(50000/64)
#define NSCB 128                        // scatter blocks
#define EPB (N_EDGES / NSCB)            // 6250 edges per scatter block
#define RCAP 32                         // slots per (block,bucket) run (mean 8)
#define LIN1B ((N_NODES + 63) / 64)     // 782 lin1 blocks
#define HEADB ((N_NODES + 127) / 128)   // 391 head blocks (128 nodes each)
// preconverted fp16 weight image offsets (in halves)
#define W2T_OFF  0                      // 32 rows x 40
#define FW1T_OFF 1280                   // 64 rows x 40
#define FW2T_OFF 3840                   // 128 rows x 72
#define WIMG_LEN 13056                  // total halves (26112 B, /8 = 1632 uint4)

typedef _Float16 f16x8 __attribute__((ext_vector_type(8)));
typedef float f32x4 __attribute__((ext_vector_type(4)));

union H8 { uint4 v; unsigned int u[4]; f16x8 h; };

__device__ __forceinline__ f32x4 MM(const H8& a, const H8& b, f32x4 c) {
    return __builtin_amdgcn_mfma_f32_16x16x32_f16(a.h, b.h, c, 0, 0, 0);
}
__device__ __forceinline__ unsigned int pkh(float a, float b) {
    __half2 h = __floats2half2_rn(a, b);
    unsigned int u;
    __builtin_memcpy(&u, &h, 4);
    return u;
}

// ---- K1 (fused roles): [0,NSCB) edge scatter; [NSCB,NSCB+LIN1B) MFMA lin1;
// last block converts head weights to the padded fp16 LDS image in whd. ----
__global__ __launch_bounds__(256) void k_scat_lin1(
        const int* __restrict__ src, const int* __restrict__ dst,
        unsigned int* __restrict__ staging, int* __restrict__ counts,
        const float* __restrict__ x,
        const float* __restrict__ w1n, const float* __restrict__ w1r,
        const float* __restrict__ b1,
        const float* __restrict__ w2n, const float* __restrict__ w2r,
        const float* __restrict__ fw1, const float* __restrict__ fw2,
        __half* __restrict__ whd,
        __half* __restrict__ xw1n, __half* __restrict__ xr1b) {
    __shared__ __align__(16) unsigned char smem[4608];
    const int tid = threadIdx.x;

    if (blockIdx.x < NSCB) {
        // ---------- scatter role: single pass, LDS cursors ----------
        int* lh = (int*)smem;                      // [NBUCKET] = 3128B
        for (int i = tid; i < NBUCKET; i += 256) lh[i] = 0;
        __syncthreads();
        const int sb = blockIdx.x;
        const int base = sb * EPB;
        for (int i = tid; i < EPB; i += 256) {
            int d = dst[base + i], s = src[base + i];
            int b = d >> BSHIFT;
            int pos = atomicAdd(&lh[b], 1);        // LDS atomic
            if (pos < RCAP)
                staging[(b * NSCB + sb) * RCAP + pos] =
                    ((unsigned int)(d & (BNODES - 1)) << 16) | (unsigned int)s;
        }
        __syncthreads();
        for (int i = tid; i < NBUCKET; i += 256)
            counts[i * NSCB + sb] = min(lh[i], RCAP);
    } else if (blockIdx.x == NSCB + LIN1B) {
        // ---------- weight-conversion role: build padded fp16 image ----------
        for (int i = tid; i < 512; i += 256) {          // w2t [32][40]
            int o = i & 31, kp = i >> 5;                // kp 0..15
            float v0, v1;
            if (kp < 8) { v0 = w2n[(2 * kp) * 32 + o];      v1 = w2n[(2 * kp + 1) * 32 + o]; }
            else        { v0 = w2r[(2 * kp - 16) * 32 + o]; v1 = w2r[(2 * kp - 15) * 32 + o]; }
            *(unsigned int*)(whd + W2T_OFF + o * 40 + 2 * kp) = pkh(v0, v1);
        }
        for (int i = tid; i < 1024; i += 256) {         // fw1t [64][40]
            int o = i & 63, kp = i >> 6;                // kp 0..15
            *(unsigned int*)(whd + FW1T_OFF + o * 40 + 2 * kp) =
                pkh(fw1[(2 * kp) * 64 + o], fw1[(2 * kp + 1) * 64 + o]);
        }
        for (int i = tid; i < 4096; i += 256) {         // fw2t [128][72]
            int o = i & 127, kp = i >> 7;               // kp 0..31
            *(unsigned int*)(whd + FW2T_OFF + o * 72 + 2 * kp) =
                pkh(fw2[(2 * kp) * 128 + o], fw2[(2 * kp + 1) * 128 + o]);
        }
    } else {
        // ---------- lin1 role (MFMA): wave = 16 nodes ----------
        __half* s_w1t = (__half*)smem;             // [out 32][k 64 pad 72]
        for (int i = tid; i < 1024; i += 256) {    // pack pairs along k
            int o = i & 31, kp = i >> 5;
            const float* W = (o < 16) ? (w1n + o) : (w1r + (o - 16));
            *(unsigned int*)(s_w1t + o * 72 + 2 * kp) =
                pkh(W[(2 * kp) * 16], W[(2 * kp + 1) * 16]);
        }
        __syncthreads();
        const int l = tid & 63, li = l & 15, g = l >> 4;
        const int wid = tid >> 6;
        const int node = (blockIdx.x - NSCB) * 64 + wid * 16 + li;
        const int nodec = node < N_NODES ? node : N_NODES - 1;

        H8 B0, B1;
        {
            const float4* xp = (const float4*)(x + nodec * 64 + 8 * g);
            float4 v0 = xp[0], v1 = xp[1];
            B0.u[0] = pkh(v0.x, v0.y); B0.u[1] = pkh(v0.z, v0.w);
            B0.u[2] = pkh(v1.x, v1.y); B0.u[3] = pkh(v1.z, v1.w);
            const float4* xq = (const float4*)(x + nodec * 64 + 32 + 8 * g);
            float4 w0 = xq[0], w1 = xq[1];
            B1.u[0] = pkh(w0.x, w0.y); B1.u[1] = pkh(w0.z, w0.w);
            B1.u[2] = pkh(w1.x, w1.y); B1.u[3] = pkh(w1.z, w1.w);
        }
        H8 A;
        f32x4 c0 = {0.f, 0.f, 0.f, 0.f};                   // -> xw1n
        A.v = *(const uint4*)(s_w1t + li * 72 + 8 * g);
        c0 = MM(A, B0, c0);
        A.v = *(const uint4*)(s_w1t + li * 72 + 32 + 8 * g);
        c0 = MM(A, B1, c0);
        f32x4 c1 = *(const f32x4*)(b1 + 4 * g);            // -> xr1b (+b1)
        A.v = *(const uint4*)(s_w1t + (16 + li) * 72 + 8 * g);
        c1 = MM(A, B0, c1);
        A.v = *(const uint4*)(s_w1t + (16 + li) * 72 + 32 + 8 * g);
        c1 = MM(A, B1, c1);

        if (node < N_NODES) {
            uint2 s0, s1;
            s0.x = pkh(c0[0], c0[1]); s0.y = pkh(c0[2], c0[3]);
            s1.x = pkh(c1[0], c1[1]); s1.y = pkh(c1[2], c1[3]);
            *(uint2*)(xw1n + node * 16 + 4 * g) = s0;
            *(uint2*)(xr1b + node * 16 + 4 * g) = s1;
        }
    }
}

// ---- K2: per-bucket table assembly + fused agg1 (782 blocks, 64 nodes) ----
__global__ __launch_bounds__(256) void k_buildAgg1(
        const unsigned int* __restrict__ staging, const int* __restrict__ counts,
        const __half* __restrict__ xw1n, const __half* __restrict__ xr1b,
        unsigned int* __restrict__ nbrU, int* __restrict__ deg,
        __half* __restrict__ h1) {
    __shared__ unsigned short ltbl[BNODES * MAXD];    // 8KB
    __shared__ int lcnt[BNODES];
    __shared__ int lc[NSCB];
    const int tid = threadIdx.x, b = blockIdx.x;
    if (tid < BNODES) lcnt[tid] = 0;
    for (int i = tid; i < NSCB; i += 256) lc[i] = counts[b * NSCB + i];
    __syncthreads();
    for (int i = tid; i < NSCB * RCAP; i += 256) {    // 4096 slots
        int sb = i >> 5, j = i & 31;
        if (j < lc[sb]) {
            unsigned int u = staging[(b * NSCB + sb) * RCAP + j];
            int dl = u >> 16, s = u & 0xFFFF;
            int slot = atomicAdd(&lcnt[dl], 1);
            if (slot < MAXD) ltbl[(dl << 6) + slot] = (unsigned short)s;
        }
    }
    __syncthreads();
    const int nbase = b << BSHIFT;
    // packed table write (for k_head's gather) + deg
    for (int i = tid; i < BNODES * 32; i += 256) {
        int nl = i >> 5, j = i & 31;
        int node = nbase + nl;
        if (node < N_NODES && 2 * j < lcnt[nl]) {
            unsigned int lo = ltbl[(nl << 6) + 2 * j];
            unsigned int hi = ltbl[(nl << 6) + 2 * j + 1];
            nbrU[(node << 5) + j] = lo | (hi << 16);
        }
    }
    if (tid < BNODES && nbase + tid < N_NODES) deg[nbase + tid] = lcnt[tid];
    // fused agg1: h1 = relu(mean_nbrs(xw1n) + xr1b); 8 half2-lanes/node
    for (int i = tid; i < BNODES * 8; i += 256) {     // 512 items, 2/thread
        int nl = i >> 3, fp = i & 7;
        int node = nbase + nl;
        if (node >= N_NODES) continue;
        int c = lcnt[nl];
        float inv = c > 0 ? 1.f / (float)c : 1.f;
        int cc = c > MAXD ? MAXD : c;
        const unsigned short* np = ltbl + (nl << 6);  // LDS broadcast reads
        float2 a0 = {0.f, 0.f}, a1 = {0.f, 0.f}, a2 = {0.f, 0.f}, a3 = {0.f, 0.f};
        int j = 0;
        for (; j + 4 <= cc; j += 4) {
            float2 v0 = __half22float2(*(const __half2*)(xw1n + (np[j + 0] << 4) + (fp << 1)));
            float2 v1 = __half22float2(*(const __half2*)(xw1n + (np[j + 1] << 4) + (fp << 1)));
            float2 v2 = __half22float2(*(const __half2*)(xw1n + (np[j + 2] << 4) + (fp << 1)));
            float2 v3 = __half22float2(*(const __half2*)(xw1n + (np[j + 3] << 4) + (fp << 1)));
            a0.x += v0.x; a0.y += v0.y; a1.x += v1.x; a1.y += v1.y;
            a2.x += v2.x; a2.y += v2.y; a3.x += v3.x; a3.y += v3.y;
        }
        for (; j < cc; ++j) {
            float2 v = __half22float2(*(const __half2*)(xw1n + (np[j] << 4) + (fp << 1)));
            a0.x += v.x; a0.y += v.y;
        }
        float2 r = __half22float2(*(const __half2*)(xr1b + (node << 4) + (fp << 1)));
        float rx = fmaxf((a0.x + a1.x + a2.x + a3.x) * inv + r.x, 0.f);
        float ry = fmaxf((a0.y + a1.y + a2.y + a3.y) * inv + r.y, 0.f);
        *(__half2*)(h1 + (node << 4) + (fp << 1)) = __floats2half2_rn(rx, ry);
    }
}

// ---- K3 (k_head, MFMA): inline agg2 gather + SAGE2 + MLP head ----
// 512 threads = 8 waves = 128 nodes/block; weights from preconverted image.
__global__ __launch_bounds__(512) void k_head(
        const __half* __restrict__ h1,
        const int* __restrict__ deg, const unsigned short* __restrict__ nbr,
        const __half* __restrict__ whd,
        const float* __restrict__ b2, const float* __restrict__ fb1,
        const float* __restrict__ fb2,
        const float* __restrict__ fw3, const float* __restrict__ fb3,
        float* __restrict__ out) {
    __shared__ __align__(16) __half s_w[WIMG_LEN];    // 26112 B

    const int tid = threadIdx.x;
    for (int i = tid; i < WIMG_LEN / 8; i += 512)     // 1632 uint4 copies
        ((uint4*)s_w)[i] = ((const uint4*)whd)[i];
    __syncthreads();
    const __half* s_w2t  = s_w + W2T_OFF;
    const __half* s_fw1t = s_w + FW1T_OFF;
    const __half* s_fw2t = s_w + FW2T_OFF;

    const int l = tid & 63, li = l & 15, g = l >> 4;
    const int wid = tid >> 6;                         // 0..7
    const int nbase = blockIdx.x * 128 + wid * 16;
    const int node = nbase + li;
    const int nodec = node < N_NODES ? node : N_NODES - 1;
    const int sl0 = li + 32 * (g & 1), sl1 = sl0 + 16;
    const int tsel = g >> 1;

    // ---- inline agg2 gather (all 64 lanes of each wave) ----
    unsigned int ua0, ua1;
    {
        const int gnode = nbase + (l >> 2);
        const int gn = gnode < N_NODES ? gnode : N_NODES - 1;
        int c = deg[gn];
        float inv = c > 0 ? 1.f / (float)c : 1.f;
        int cc = c > MAXD ? MAXD : c;
        const unsigned short* np = nbr + (gn << 6);
        const int fo = (l & 3) << 2;                  // feat offset 0/4/8/12
        float ax = 0.f, ay = 0.f, az = 0.f, aw = 0.f;
        int j = 0;
        for (; j + 2 <= cc; j += 2) {
            const __half2* h0 = (const __half2*)(h1 + (np[j] << 4) + fo);
            const __half2* h1p = (const __half2*)(h1 + (np[j + 1] << 4) + fo);
            float2 v0 = __half22float2(h0[0]), v1 = __half22float2(h0[1]);
            float2 w0 = __half22float2(h1p[0]), w1 = __half22float2(h1p[1]);
            ax += v0.x + w0.x; ay += v0.y + w0.y;
            az += v1.x + w1.x; aw += v1.y + w1.y;
        }
        if (j < cc) {
            const __half2* h0 = (const __half2*)(h1 + (np[j] << 4) + fo);
            float2 v0 = __half22float2(h0[0]), v1 = __half22float2(h0[1]);
            ax += v0.x; ay += v0.y; az += v1.x; aw += v1.y;
        }
        ua0 = pkh(ax * inv, ay * inv);
        ua1 = pkh(az * inv, aw * inv);
    }
    // transpose into B-frag: lane (li,g<2) gets agg2[li][8g..8g+7]
    H8 Bz;
    {
        const int sl = (li << 2) + ((g & 1) << 1);
        Bz.u[0] = (unsigned int)__shfl((int)ua0, sl);
        Bz.u[1] = (unsigned int)__shfl((int)ua1, sl);
        Bz.u[2] = (unsigned int)__shfl((int)ua0, sl + 1);
        Bz.u[3] = (unsigned int)__shfl((int)ua1, sl + 1);
        if (g >= 2)                                   // k>=16 -> h1 direct
            Bz.v = *(const uint4*)(h1 + (nodec << 4) + ((g & 1) << 3));
    }

    // ---- h2 = relu(z @ W2cat + b2): 2 M-tiles, K=32 ----
    unsigned int p01[2], p23[2];
#pragma unroll
    for (int t = 0; t < 2; ++t) {
        f32x4 c = *(const f32x4*)(b2 + 16 * t + 4 * g);
        H8 A; A.v = *(const uint4*)(s_w2t + (16 * t + li) * 40 + 8 * g);
        c = MM(A, Bz, c);
        p01[t] = pkh(fmaxf(c[0], 0.f), fmaxf(c[1], 0.f));
        p23[t] = pkh(fmaxf(c[2], 0.f), fmaxf(c[3], 0.f));
    }
    H8 Bh2;
    {
        unsigned int a, b;
        a = __shfl((int)p01[0], sl0); b = __shfl((int)p01[1], sl0); Bh2.u[0] = tsel ? b : a;
        a = __shfl((int)p23[0], sl0); b = __shfl((int)p23[1], sl0); Bh2.u[1] = tsel ? b : a;
        a = __shfl((int)p01[0], sl1); b = __shfl((int)p01[1], sl1); Bh2.u[2] = tsel ? b : a;
        a = __shfl((int)p23[0], sl1); b = __shfl((int)p23[1], sl1); Bh2.u[3] = tsel ? b : a;
    }

    // ---- h3 = relu(h2 @ fw1 + fb1): 4 M-tiles, K=32 ----
    unsigned int q01[4], q23[4];
#pragma unroll
    for (int t = 0; t < 4; ++t) {
        f32x4 c = *(const f32x4*)(fb1 + 16 * t + 4 * g);
        H8 A; A.v = *(const uint4*)(s_fw1t + (16 * t + li) * 40 + 8 * g);
        c = MM(A, Bh2, c);
        q01[t] = pkh(fmaxf(c[0], 0.f), fmaxf(c[1], 0.f));
        q23[t] = pkh(fmaxf(c[2], 0.f), fmaxf(c[3], 0.f));
    }
    H8 Bh3[2];
#pragma unroll
    for (int s = 0; s < 2; ++s) {
        unsigned int a, b;
        a = __shfl((int)q01[2 * s], sl0); b = __shfl((int)q01[2 * s + 1], sl0); Bh3[s].u[0] = tsel ? b : a;
        a = __shfl((int)q23[2 * s], sl0); b = __shfl((int)q23[2 * s + 1], sl0); Bh3[s].u[1] = tsel ? b : a;
        a = __shfl((int)q01[2 * s], sl1); b = __shfl((int)q01[2 * s + 1], sl1); Bh3[s].u[2] = tsel ? b : a;
        a = __shfl((int)q23[2 * s], sl1); b = __shfl((int)q23[2 * s + 1], sl1); Bh3[s].u[3] = tsel ? b : a;
    }

    // ---- h4 = relu(h3 @ fw2 + fb2); out = h4 @ fw3: 8 M-tiles, K=64 ----
    float o0 = 0.f, o1 = 0.f;
#pragma unroll
    for (int m = 0; m < 8; ++m) {
        f32x4 c = *(const f32x4*)(fb2 + 16 * m + 4 * g);
        H8 A;
        A.v = *(const uint4*)(s_fw2t + (16 * m + li) * 72 + 8 * g);
        c = MM(A, Bh3[0], c);
        A.v = *(const uint4*)(s_fw2t + (16 * m + li) * 72 + 32 + 8 * g);
        c = MM(A, Bh3[1], c);
        const float4* wp = (const float4*)(fw3 + (16 * m + 4 * g) * 2);
        float4 wA = wp[0], wB = wp[1];
        float r0 = fmaxf(c[0], 0.f), r1 = fmaxf(c[1], 0.f);
        float r2 = fmaxf(c[2], 0.f), r3 = fmaxf(c[3], 0.f);
        o0 += r0 * wA.x + r1 * wA.z + r2 * wB.x + r3 * wB.z;
        o1 += r0 * wA.y + r1 * wA.w + r2 * wB.y + r3 * wB.w;
    }
    o0 += __shfl_xor(o0, 16); o0 += __shfl_xor(o0, 32);
    o1 += __shfl_xor(o1, 16); o1 += __shfl_xor(o1, 32);
    if (g == 0 && node < N_NODES) {
        float2 r; r.x = o0 + fb3[0]; r.y = o1 + fb3[1];
        *(float2*)(out + node * 2) = r;
    }
}

extern "C" void kernel_launch(void* const* d_in, const int* in_sizes, int n_in,
                              void* d_out, int out_size, void* d_ws, size_t ws_size,
                              hipStream_t stream) {
    const float* x   = (const float*)d_in[0];
    const int*   ei  = (const int*)d_in[1];
    const int*   src = ei;
    const int*   dst = ei + N_EDGES;
    const float* w1n = (const float*)d_in[2];
    const float* w1r = (const float*)d_in[3];
    const float* b1  = (const float*)d_in[4];
    const float* w2n = (const float*)d_in[5];
    const float* w2r = (const float*)d_in[6];
    const float* b2  = (const float*)d_in[7];
    const float* fw1 = (const float*)d_in[8];
    const float* fb1 = (const float*)d_in[9];
    const float* fw2 = (const float*)d_in[10];
    const float* fb2 = (const float*)d_in[11];
    const float* fw3 = (const float*)d_in[12];
    const float* fb3 = (const float*)d_in[13];
    float* out = (float*)d_out;

    // workspace (~24.7 MB); every consumed cell is freshly written each call
    unsigned int* staging = (unsigned int*)d_ws;                     // 782*128*32 (12.8MB)
    int*          counts  = (int*)(staging + NBUCKET * NSCB * RCAP); // 100096
    unsigned int* nbrU    = (unsigned int*)(counts + NBUCKET * NSCB);// 50000*32 (6.4MB)
    int*          deg     = (int*)(nbrU + N_NODES * 32);             // 50000
    __half*       xw1n    = (__half*)(deg + N_NODES);                // 800000
    __half*       xr1b    = xw1n + N_EDGES;                          // 800000
    __half*       h1      = xr1b + N_EDGES;                          // 800000
    __half*       whd     = h1 + N_EDGES;                            // 13056 (+16B align ok)

    const unsigned short* nbr = (const unsigned short*)nbrU;

    k_scat_lin1<<<NSCB + LIN1B + 1, 256, 0, stream>>>(src, dst, staging, counts,
                                                      x, w1n, w1r, b1,
                                                      w2n, w2r, fw1, fw2, whd,
                                                      xw1n, xr1b);
    k_buildAgg1<<<NBUCKET, 256, 0, stream>>>(staging, counts, xw1n, xr1b,
                                             nbrU, deg, h1);
    k_head<<<HEADB, 512, 0, stream>>>(h1, deg, nbr, whd, b2, fb1, fb2,
                                      fw3, fb3, out);
}